// Round 9
// baseline (472.530 us; speedup 1.0000x reference)
//
#include <hip/hip_runtime.h>
#include <math.h>

#define NW 100000
#define NS 10000
#define NE 800000
#define DIM 256
#define NH 4
#define DFF 512
#define NEG_SLOPE 0.2f
#define CAP 64   // bucket capacity; deg ~ Poisson(8), P(>64) ~ 0

#define SC_B 3125        // scatter blocks (NE/256)

typedef __attribute__((ext_vector_type(8))) short bf16x8;
typedef __attribute__((ext_vector_type(8))) unsigned short ushortx8;
typedef __attribute__((ext_vector_type(16))) float floatx16;
typedef __attribute__((ext_vector_type(4))) float floatx4;

// ---------------- helpers ----------------
__device__ __forceinline__ unsigned short f2bf(float f) {  // RNE fp32->bf16
    unsigned int u = __float_as_uint(f);
    unsigned int r = (u + 0x7fffu + ((u >> 16) & 1u)) >> 16;
    return (unsigned short)r;
}
__device__ __forceinline__ float bf2f(unsigned short u) {
    return __uint_as_float(((unsigned int)u) << 16);
}
__device__ __forceinline__ void gload_lds16(const void* g, void* l) {
    __builtin_amdgcn_global_load_lds(
        (const __attribute__((address_space(1))) unsigned int*)g,
        (__attribute__((address_space(3))) unsigned int*)l, 16, 0, 0);
}
// packs (lo,hi) -> [15:0]=bf16(lo), [31:16]=bf16(hi), RNE
__device__ __forceinline__ unsigned int cvt_pk_bf16(float lo, float hi) {
    unsigned int d;
    asm("v_cvt_pk_bf16_f32 %0, %1, %2" : "=v"(d) : "v"(lo), "v"(hi));
    return d;
}
// a'[i+32] = b[i]; b'[i] = a[i+32]
__device__ __forceinline__ void permlane32_swap(unsigned int& a, unsigned int& b) {
    asm("v_permlane32_swap_b32 %0, %1" : "+v"(a), "+v"(b));
}

// ---------------- prep: C_dst, fragment-packed weights ----------------
// blocks: [0,1) compute_C | [1,769) w1p/w2p | [769,1025) wsp (W_src bf16 octets)
__global__ __launch_bounds__(256) void prep_all(
    const float* __restrict__ W_src, const float* __restrict__ W_dst,
    const float* __restrict__ attn_r, const float* __restrict__ w1,
    const float* __restrict__ w2,
    float* __restrict__ C_dst,
    unsigned short* __restrict__ w1p, unsigned short* __restrict__ w2p,
    unsigned short* __restrict__ wsp)
{
    int b = blockIdx.x, t = threadIdx.x;
    if (b < 1) {
        // C_dst[k,h] = sum_d W_dst[k, h*64+d] * attn_r[h,d]
        int k = t;
#pragma unroll
        for (int h = 0; h < NH; h++) {
            const float4* Wv = (const float4*)(W_dst + (size_t)k * DIM + h * 64);
            const float4* Av = (const float4*)(attn_r + h * 64);
            float s = 0.f;
#pragma unroll
            for (int d = 0; d < 16; d++) {
                float4 w = Wv[d], a = Av[d];
                s += w.x * a.x + w.y * a.y + w.z * a.z + w.w * a.w;
            }
            C_dst[k * NH + h] = s;
        }
    } else if (b < 1 + DFF + 256) {
        // fragment-packed FFN weights, octet layout [k>>3][n][k&7]
        int bb = b - 1;
        if (bb < DFF) {
            int n = bb, k = t;   // w1[k][n]
            w1p[((size_t)(k >> 3) * 512 + n) * 8 + (k & 7)] = f2bf(w1[(size_t)k * DFF + n]);
        } else {
            int c = bb - DFF;    // w2[k2][c]
#pragma unroll
            for (int kk = 0; kk < 2; kk++) {
                int k2 = t + kk * 256;
                w2p[((size_t)(k2 >> 3) * 256 + c) * 8 + (k2 & 7)] = f2bf(w2[(size_t)k2 * 256 + c]);
            }
        }
    } else {
        // wsp: W_src bf16 octet layout [k>>3][c][k&7]
        int c = b - (1 + DFF + 256);
        int k = t;
        wsp[((size_t)(k >> 3) * 256 + c) * 8 + (k & 7)] = f2bf(W_src[(size_t)k * DIM + c]);
    }
}

// ---------------- feat16 = bf16(sent @ W_src) via MFMA, el fused ----------
__global__ __launch_bounds__(256) void feat_el(
    const float* __restrict__ sent, const unsigned short* __restrict__ wsp,
    const float* __restrict__ attn_l,
    unsigned short* __restrict__ feat16, float* __restrict__ el)
{
    __shared__ unsigned short As[32][16][8];   // [k>>3][row][k&7], 8 KB
    int t = threadIdx.x;
    int lane = t & 63, wv = t >> 6;
    int l15 = lane & 15, l4 = lane >> 4;
    size_t row0 = (size_t)blockIdx.x * 16;

    // stage A: thread t -> row t&15, col-group t>>4 (16 cols), bf16-converted
    {
        int r = t & 15, cg = t >> 4;
        const float* srow = sent + (row0 + r) * DIM + cg * 16;
        float4 v0 = *(const float4*)(srow + 0);
        float4 v1 = *(const float4*)(srow + 4);
        float4 v2 = *(const float4*)(srow + 8);
        float4 v3 = *(const float4*)(srow + 12);
        union { unsigned int u[4]; ushortx8 v; } p0, p1;
        p0.u[0] = cvt_pk_bf16(v0.x, v0.y); p0.u[1] = cvt_pk_bf16(v0.z, v0.w);
        p0.u[2] = cvt_pk_bf16(v1.x, v1.y); p0.u[3] = cvt_pk_bf16(v1.z, v1.w);
        p1.u[0] = cvt_pk_bf16(v2.x, v2.y); p1.u[1] = cvt_pk_bf16(v2.z, v2.w);
        p1.u[2] = cvt_pk_bf16(v3.x, v3.y); p1.u[3] = cvt_pk_bf16(v3.z, v3.w);
        *(ushortx8*)&As[cg * 2][r][0] = p0.v;
        *(ushortx8*)&As[cg * 2 + 1][r][0] = p1.v;
    }
    __syncthreads();

    floatx4 acc[4];
#pragma unroll
    for (int nt = 0; nt < 4; nt++) acc[nt] = (floatx4)(0.f);
    const bf16x8* wv8 = (const bf16x8*)wsp;
#pragma unroll
    for (int step = 0; step < 8; step++) {
        bf16x8 a = *(const bf16x8*)&As[l4 + step * 4][l15][0];
#pragma unroll
        for (int nt = 0; nt < 4; nt++) {
            int c = wv * 64 + nt * 16 + l15;
            bf16x8 bfr = wv8[(size_t)(l4 + step * 4) * 256 + c];
            acc[nt] = __builtin_amdgcn_mfma_f32_16x16x32_bf16(a, bfr, acc[nt], 0, 0, 0);
        }
    }
    // C layout: col = lane&15 (per n-tile), row = (lane>>4)*4 + reg
    float ep[4] = {0.f, 0.f, 0.f, 0.f};
#pragma unroll
    for (int nt = 0; nt < 4; nt++) {
        int c = wv * 64 + nt * 16 + l15;
        float al = attn_l[c];
#pragma unroll
        for (int r = 0; r < 4; r++) {
            int row = (int)row0 + l4 * 4 + r;
            feat16[(size_t)row * DIM + c] = f2bf(acc[nt][r]);
            ep[r] = fmaf(acc[nt][r], al, ep[r]);
        }
    }
#pragma unroll
    for (int m = 1; m < 16; m <<= 1) {
#pragma unroll
        for (int r = 0; r < 4; r++) ep[r] += __shfl_xor(ep[r], m, 64);
    }
    if (l15 == 0) {
#pragma unroll
        for (int r = 0; r < 4; r++)
            el[((size_t)row0 + l4 * 4 + r) * NH + wv] = ep[r];
    }
}

// ---------------- scatter ----------------
__global__ void scatter_edges(const int* __restrict__ src, const int* __restrict__ dst,
                              int* __restrict__ count, unsigned short* __restrict__ bucket) {
    int e = blockIdx.x * 256 + threadIdx.x;
    if (e >= NE) return;
    int w = dst[e];
    int pos = atomicAdd(&count[w], 1);
    if (pos < CAP) bucket[(size_t)w * CAP + pos] = (unsigned short)src[e];
}

// ---------------- GAT v2: ONE node per wave, async-staged gather ----------
__global__ __launch_bounds__(256) void gat_h(
    const int* __restrict__ count, const unsigned short* __restrict__ bucket,
    const float* __restrict__ el, const float* __restrict__ Cdst,
    const unsigned short* __restrict__ feat16, const float* __restrict__ word,
    const float* __restrict__ gat_bias, unsigned short* hb, int node0)
{
    __shared__ unsigned short Fs[4][8][256];  // staged feat rows, 16 KB
    __shared__ float abuf[4][64][4];          // alpha[slot][head], 4 KB
    int tid = threadIdx.x;
    int lane = tid & 63, wv = tid >> 6;
    int node = node0 + blockIdx.x * 4 + wv;

    // ---- speculative early issues ----
    int deg = count[node];
    int sraw = bucket[(size_t)node * CAP + lane];
    float4 wrow = *(const float4*)(word + (size_t)node * DIM + lane * 4);
    int s = sraw < NS ? sraw : NS - 1;
    float4 el4 = *(const float4*)(el + (size_t)s * 4);

    // ---- stage first 8 feat rows to LDS (overlaps er/softmax below) ----
#pragma unroll
    for (int j = 0; j < 4; j++) {
        int sA = __shfl(s, 2 * j, 64);
        int sB = __shfl(s, 2 * j + 1, 64);
        int srow = (lane < 32) ? sA : sB;
        gload_lds16(feat16 + (size_t)srow * DIM + (lane & 31) * 8, &Fs[wv][2 * j][0]);
    }

    // ---- er[h] = sum_c word[c] * Cdst[c][h], reduced over 64 lanes ----
    const float4* Cv = (const float4*)Cdst;
    float p0 = 0.f, p1 = 0.f, p2 = 0.f, p3 = 0.f;
    {
        float wc[4] = {wrow.x, wrow.y, wrow.z, wrow.w};
#pragma unroll
        for (int j = 0; j < 4; j++) {
            float4 ch = Cv[lane * 4 + j];
            p0 = fmaf(wc[j], ch.x, p0); p1 = fmaf(wc[j], ch.y, p1);
            p2 = fmaf(wc[j], ch.z, p2); p3 = fmaf(wc[j], ch.w, p3);
        }
    }
#pragma unroll
    for (int m = 1; m < 64; m <<= 1) {
        p0 += __shfl_xor(p0, m, 64); p1 += __shfl_xor(p1, m, 64);
        p2 += __shfl_xor(p2, m, 64); p3 += __shfl_xor(p3, m, 64);
    }

    // ---- scores: slot = lane; exp directly (bounded, no max pass) ----
    int dg = deg > CAP ? CAP : deg;
    float x0 = 0.f, x1 = 0.f, x2 = 0.f, x3 = 0.f;
    if (lane < dg) {
        float v;
        v = el4.x + p0; x0 = __expf(v > 0.f ? v : NEG_SLOPE * v);
        v = el4.y + p1; x1 = __expf(v > 0.f ? v : NEG_SLOPE * v);
        v = el4.z + p2; x2 = __expf(v > 0.f ? v : NEG_SLOPE * v);
        v = el4.w + p3; x3 = __expf(v > 0.f ? v : NEG_SLOPE * v);
    }
    float d0 = x0, d1 = x1, d2 = x2, d3 = x3;
#pragma unroll
    for (int m = 1; m < 64; m <<= 1) {
        d0 += __shfl_xor(d0, m, 64); d1 += __shfl_xor(d1, m, 64);
        d2 += __shfl_xor(d2, m, 64); d3 += __shfl_xor(d3, m, 64);
    }
    float4 av;
    av.x = x0 * (1.f / d0); av.y = x1 * (1.f / d1);
    av.z = x2 * (1.f / d2); av.w = x3 * (1.f / d3);
    *(float4*)&abuf[wv][lane][0] = av;   // NaN if dg==0, never read

    // ---- gather: 4 cols per lane; staged slots from LDS, tail from global ----
    int hh = lane >> 4;
    float a0 = 0.f, a1 = 0.f, a2 = 0.f, a3 = 0.f;
    asm volatile("s_waitcnt vmcnt(0)" ::: "memory");  // staged rows landed
    int nst = dg < 8 ? dg : 8;
    for (int i = 0; i < nst; i++) {
        float aa = abuf[wv][i][hh];
        ushort4 f = *(const ushort4*)&Fs[wv][i][lane * 4];
        a0 = fmaf(aa, bf2f(f.x), a0); a1 = fmaf(aa, bf2f(f.y), a1);
        a2 = fmaf(aa, bf2f(f.z), a2); a3 = fmaf(aa, bf2f(f.w), a3);
    }
    for (int i = 8; i < dg; i++) {
        int si = __shfl(s, i, 64);
        float aa = abuf[wv][i][hh];
        ushort4 f = *(const ushort4*)&feat16[(size_t)si * DIM + lane * 4];
        a0 = fmaf(aa, bf2f(f.x), a0); a1 = fmaf(aa, bf2f(f.y), a1);
        a2 = fmaf(aa, bf2f(f.z), a2); a3 = fmaf(aa, bf2f(f.w), a3);
    }

    // ---- epilogue: +bias, ELU, +residual, bf16 store ----
    float4 gb = *(const float4*)(gat_bias + lane * 4);
    float r0 = a0 + gb.x, r1 = a1 + gb.y, r2 = a2 + gb.z, r3 = a3 + gb.w;
    r0 = r0 > 0.f ? r0 : (__expf(r0) - 1.f);
    r1 = r1 > 0.f ? r1 : (__expf(r1) - 1.f);
    r2 = r2 > 0.f ? r2 : (__expf(r2) - 1.f);
    r3 = r3 > 0.f ? r3 : (__expf(r3) - 1.f);
    unsigned int lo = cvt_pk_bf16(wrow.x + r0, wrow.y + r1);
    unsigned int hi = cvt_pk_bf16(wrow.z + r2, wrow.w + r3);
    uint2 o; o.x = lo; o.y = hi;
    *(uint2*)&hb[(size_t)node * 512 + 256 + lane * 4] = o;
}

// ---------------- Fused FFN v4: BM=128, 4 waves, dual-acc G1 ----------------
// 782 blocks (fine-grained dynamic packing vs v3's 391), 2 blocks/CU resident.
// Per wave: 32 rows x 256 out cols, H in regs, weights LDS-double-buffered.
// G1 accumulates into two registers (even/odd ks) halving the serial MFMA
// dependency chain, summed once before the pack.
__global__ __launch_bounds__(256, 2) void ffn_fused4(
    const unsigned short* hb,                // = (ushort*)d_out (aliases out!)
    const unsigned short* __restrict__ w1p,
    const float* __restrict__ b1,
    const unsigned short* __restrict__ w2p,
    const float* __restrict__ b2,
    float* out)
{
    __shared__ unsigned short W1s[2][8192];  // 16 KB each buf
    __shared__ unsigned short W2s[2][8192];
    int tid = threadIdx.x;
    int lane = tid & 63, wv = tid >> 6;      // wv 0..3
    int l31 = lane & 31, half = lane >> 5;
    int row0 = blockIdx.x * 128;

    // ---- H rows -> registers ----
    int myrow = row0 + wv * 32 + l31;
    if (myrow >= NW) myrow = NW - 1;
    const unsigned short* hrow = hb + (size_t)myrow * 512 + 256 + half * 8;
    bf16x8 hreg[16];
#pragma unroll
    for (int ks = 0; ks < 16; ks++)
        hreg[ks] = *(const bf16x8*)(hrow + ks * 16);

    // ---- stage chunk 0 (all 4 waves cooperate; 8 gload calls per wave) ----
    {
#pragma unroll
        for (int it = 0; it < 4; it++) {
            int q0 = (wv * 4 + it) * 64;
            int q = q0 + lane;
            int ko = q >> 5, np = q & 31;
            gload_lds16(w1p + ((size_t)ko * 512 + np) * 8, &W1s[0][q0 * 8]);
        }
#pragma unroll
        for (int it = 0; it < 4; it++) {
            int q0 = (wv * 4 + it) * 64;
            gload_lds16(w2p + ((size_t)(q0 + lane)) * 8, &W2s[0][q0 * 8]);
        }
    }

    floatx16 oacc[8];
#pragma unroll
    for (int j = 0; j < 8; j++) oacc[j] = (floatx16)(0.f);
    __syncthreads();

#pragma unroll 2
    for (int hbi = 0; hbi < 16; hbi++) {
        int cur = hbi & 1;
        // ---- stage next chunk into buf^1 ----
        if (hbi < 15) {
            int c = hbi + 1, nb = cur ^ 1;
#pragma unroll
            for (int it = 0; it < 4; it++) {
                int q0 = (wv * 4 + it) * 64;
                int q = q0 + lane;
                int ko = q >> 5, np = q & 31;
                gload_lds16(w1p + ((size_t)ko * 512 + c * 32 + np) * 8, &W1s[nb][q0 * 8]);
            }
#pragma unroll
            for (int it = 0; it < 4; it++) {
                int q0 = (wv * 4 + it) * 64;
                gload_lds16(w2p + ((size_t)c * 1024 + q0 + lane) * 8, &W2s[nb][q0 * 8]);
            }
        }
        // ---- G1 swapped, dual accumulator (halved dependency chain) ----
        const bf16x8* W1v = (const bf16x8*)W1s[cur];
        floatx16 h0 = (floatx16)(0.f), h1 = (floatx16)(0.f);
#pragma unroll
        for (int ks = 0; ks < 16; ks += 2) {
            bf16x8 a0 = W1v[(ks * 2 + half) * 32 + l31];
            bf16x8 a1 = W1v[((ks + 1) * 2 + half) * 32 + l31];
            h0 = __builtin_amdgcn_mfma_f32_32x32x16_bf16(a0, hreg[ks], h0, 0, 0, 0);
            h1 = __builtin_amdgcn_mfma_f32_32x32x16_bf16(a1, hreg[ks + 1], h1, 0, 0, 0);
        }
        floatx16 hacc = h0 + h1;
        // ---- bias + relu; reg j holds hid = (j&3)+8*(j>>2)+4*half ----
        const float* b1b = b1 + hbi * 32 + 4 * half;
        float4 bb0 = *(const float4*)(b1b + 0);
        float4 bb1 = *(const float4*)(b1b + 8);
        float4 bb2 = *(const float4*)(b1b + 16);
        float4 bb3 = *(const float4*)(b1b + 24);
        float bs[16] = {bb0.x, bb0.y, bb0.z, bb0.w, bb1.x, bb1.y, bb1.z, bb1.w,
                        bb2.x, bb2.y, bb2.z, bb2.w, bb3.x, bb3.y, bb3.z, bb3.w};
        float p[16];
#pragma unroll
        for (int j = 0; j < 16; j++) {
            float v = hacc[j] + bs[j];
            p[j] = v > 0.f ? v : 0.f;
        }
        // ---- pack to bf16 + half-exchange -> G2 A-frags in-register ----
        unsigned int pk0 = cvt_pk_bf16(p[0], p[1]),   pk1 = cvt_pk_bf16(p[2], p[3]);
        unsigned int pk2 = cvt_pk_bf16(p[4], p[5]),   pk3 = cvt_pk_bf16(p[6], p[7]);
        unsigned int pk4 = cvt_pk_bf16(p[8], p[9]),   pk5 = cvt_pk_bf16(p[10], p[11]);
        unsigned int pk6 = cvt_pk_bf16(p[12], p[13]), pk7 = cvt_pk_bf16(p[14], p[15]);
        permlane32_swap(pk0, pk2);
        permlane32_swap(pk1, pk3);
        permlane32_swap(pk4, pk6);
        permlane32_swap(pk5, pk7);
        union { unsigned int u[4]; bf16x8 v; } f0, f1;
        f0.u[0] = pk0; f0.u[1] = pk1; f0.u[2] = pk2; f0.u[3] = pk3;  // hid 0..15
        f1.u[0] = pk4; f1.u[1] = pk5; f1.u[2] = pk6; f1.u[3] = pk7;  // hid 16..31
        // ---- G2: oacc[ct] += P-frag @ W2-frag(LDS) ----
        const bf16x8* W2v = (const bf16x8*)W2s[cur];
#pragma unroll
        for (int ks2 = 0; ks2 < 2; ks2++) {
            bf16x8 pa = ks2 ? f1.v : f0.v;
#pragma unroll
            for (int ct = 0; ct < 8; ct++) {
                bf16x8 bfr = W2v[(ks2 * 2 + half) * 256 + ct * 32 + l31];
                oacc[ct] = __builtin_amdgcn_mfma_f32_32x32x16_bf16(pa, bfr, oacc[ct], 0, 0, 0);
            }
        }
        if (hbi < 15) __syncthreads();
    }
    // ---- epilogue: + b2, fp32 stores ----
#pragma unroll
    for (int ct = 0; ct < 8; ct++) {
        int c = ct * 32 + l31;
        float bias = b2[c];
#pragma unroll
        for (int reg = 0; reg < 16; reg++) {
            int rloc = row0 + wv * 32 + (reg & 3) + 8 * (reg >> 2) + 4 * half;
            if (rloc < NW) out[(size_t)rloc * DIM + c] = oacc[ct][reg] + bias;
        }
    }
}

// ---------------- launch ----------------
extern "C" void kernel_launch(void* const* d_in, const int* in_sizes, int n_in,
                              void* d_out, int out_size, void* d_ws, size_t ws_size,
                              hipStream_t stream) {
    const float* word   = (const float*)d_in[0];
    const float* sent   = (const float*)d_in[1];
    const int*   src    = (const int*)d_in[2];
    const int*   dst    = (const int*)d_in[3];
    const float* W_src  = (const float*)d_in[4];
    const float* W_dst  = (const float*)d_in[5];
    const float* attn_l = (const float*)d_in[6];
    const float* attn_r = (const float*)d_in[7];
    const float* gbias  = (const float*)d_in[8];
    const float* w1     = (const float*)d_in[9];
    const float* b1     = (const float*)d_in[10];
    const float* w2     = (const float*)d_in[11];
    const float* b2     = (const float*)d_in[12];
    float* out = (float*)d_out;
    // hbf row n interleaved into d_out bytes [1024n+512, 1024n+1024)
    unsigned short* hb = (unsigned short*)d_out;

    char* wsb = (char*)d_ws;
    unsigned short* w1p = (unsigned short*)wsb;                 // 512*256
    unsigned short* w2p = w1p + (size_t)DFF * 256;              // 256*512
    unsigned short* wsp = w2p + (size_t)256 * DFF;              // 256*256
    float* el    = (float*)(wsp + (size_t)DIM * DIM);           // NS*4
    float* C_dst = el + (size_t)NS * NH;                        // 256*4
    unsigned short* feat16 = (unsigned short*)(C_dst + DIM * NH);  // NS*256
    int* count = (int*)(feat16 + (size_t)NS * DIM);             // NW
    unsigned short* bucket = (unsigned short*)(count + NW);     // NW*CAP

    hipMemsetAsync(count, 0, (size_t)NW * sizeof(int), stream);
    hipLaunchKernelGGL(scatter_edges, dim3(SC_B), dim3(256), 0, stream, src, dst, count, bucket);
    hipLaunchKernelGGL(prep_all, dim3(1 + DFF + 256 + 256), dim3(256), 0, stream,
                       W_src, W_dst, attn_r, w1, w2, C_dst, w1p, w2p, wsp);
    hipLaunchKernelGGL(feat_el, dim3(NS / 16), dim3(256), 0, stream,
                       sent, wsp, attn_l, feat16, el);
    hipLaunchKernelGGL(gat_h, dim3(NW / 8), dim3(256), 0, stream,
                       count, bucket, el, C_dst, feat16, word, gbias, hb, 0);
    hipLaunchKernelGGL(gat_h, dim3(NW / 8), dim3(256), 0, stream,
                       count, bucket, el, C_dst, feat16, word, gbias, hb, NW / 2);
    hipLaunchKernelGGL(ffn_fused4, dim3((NW + 127) / 128), dim3(256), 0, stream,
                       hb, w1p, b1, w2p, b2, out);
}

// Round 10
// 427.128 us; speedup vs baseline: 1.1063x; 1.1063x over previous
//
#include <hip/hip_runtime.h>
#include <math.h>

#define NW 100000
#define NS 10000
#define NE 800000
#define DIM 256
#define NH 4
#define DFF 512
#define NEG_SLOPE 0.2f
#define CAP 64   // bucket capacity; deg ~ Poisson(8), P(>64) ~ 0

typedef __attribute__((ext_vector_type(8))) short bf16x8;
typedef __attribute__((ext_vector_type(8))) unsigned short ushortx8;
typedef __attribute__((ext_vector_type(16))) float floatx16;
typedef __attribute__((ext_vector_type(4))) float floatx4;

// ---------------- helpers ----------------
__device__ __forceinline__ unsigned short f2bf(float f) {  // RNE fp32->bf16
    unsigned int u = __float_as_uint(f);
    unsigned int r = (u + 0x7fffu + ((u >> 16) & 1u)) >> 16;
    return (unsigned short)r;
}
__device__ __forceinline__ float bf2f(unsigned short u) {
    return __uint_as_float(((unsigned int)u) << 16);
}
__device__ __forceinline__ void gload_lds16(const void* g, void* l) {
    __builtin_amdgcn_global_load_lds(
        (const __attribute__((address_space(1))) unsigned int*)g,
        (__attribute__((address_space(3))) unsigned int*)l, 16, 0, 0);
}
// packs (lo,hi) -> [15:0]=bf16(lo), [31:16]=bf16(hi), RNE
__device__ __forceinline__ unsigned int cvt_pk_bf16(float lo, float hi) {
    unsigned int d;
    asm("v_cvt_pk_bf16_f32 %0, %1, %2" : "=v"(d) : "v"(lo), "v"(hi));
    return d;
}
// a'[i+32] = b[i]; b'[i] = a[i+32]
__device__ __forceinline__ void permlane32_swap(unsigned int& a, unsigned int& b) {
    asm("v_permlane32_swap_b32 %0, %1" : "+v"(a), "+v"(b));
}

// ---------------- prep: C_dst, fragment-packed weights ----------------
// blocks: [0,1) compute_C | [1,769) w1p/w2p | [769,1025) wsp (W_src bf16 octets)
__global__ __launch_bounds__(256) void prep_all(
    const float* __restrict__ W_src, const float* __restrict__ W_dst,
    const float* __restrict__ attn_r, const float* __restrict__ w1,
    const float* __restrict__ w2,
    float* __restrict__ C_dst,
    unsigned short* __restrict__ w1p, unsigned short* __restrict__ w2p,
    unsigned short* __restrict__ wsp)
{
    int b = blockIdx.x, t = threadIdx.x;
    if (b < 1) {
        // C_dst[k,h] = sum_d W_dst[k, h*64+d] * attn_r[h,d]
        int k = t;
#pragma unroll
        for (int h = 0; h < NH; h++) {
            const float4* Wv = (const float4*)(W_dst + (size_t)k * DIM + h * 64);
            const float4* Av = (const float4*)(attn_r + h * 64);
            float s = 0.f;
#pragma unroll
            for (int d = 0; d < 16; d++) {
                float4 w = Wv[d], a = Av[d];
                s += w.x * a.x + w.y * a.y + w.z * a.z + w.w * a.w;
            }
            C_dst[k * NH + h] = s;
        }
    } else if (b < 1 + DFF + 256) {
        // fragment-packed FFN weights, octet layout [k>>3][n][k&7]
        int bb = b - 1;
        if (bb < DFF) {
            int n = bb, k = t;   // w1[k][n]
            w1p[((size_t)(k >> 3) * 512 + n) * 8 + (k & 7)] = f2bf(w1[(size_t)k * DFF + n]);
        } else {
            int c = bb - DFF;    // w2[k2][c]
#pragma unroll
            for (int kk = 0; kk < 2; kk++) {
                int k2 = t + kk * 256;
                w2p[((size_t)(k2 >> 3) * 256 + c) * 8 + (k2 & 7)] = f2bf(w2[(size_t)k2 * 256 + c]);
            }
        }
    } else {
        // wsp: W_src bf16 octet layout [k>>3][c][k&7]
        int c = b - (1 + DFF + 256);
        int k = t;
        wsp[((size_t)(k >> 3) * 256 + c) * 8 + (k & 7)] = f2bf(W_src[(size_t)k * DIM + c]);
    }
}

// ---------------- feat16 = bf16(sent @ W_src) via MFMA, el fused ----------
__global__ __launch_bounds__(256) void feat_el(
    const float* __restrict__ sent, const unsigned short* __restrict__ wsp,
    const float* __restrict__ attn_l,
    unsigned short* __restrict__ feat16, float* __restrict__ el)
{
    __shared__ unsigned short As[32][16][8];   // [k>>3][row][k&7], 8 KB
    int t = threadIdx.x;
    int lane = t & 63, wv = t >> 6;
    int l15 = lane & 15, l4 = lane >> 4;
    size_t row0 = (size_t)blockIdx.x * 16;

    // stage A: thread t -> row t&15, col-group t>>4 (16 cols), bf16-converted
    {
        int r = t & 15, cg = t >> 4;
        const float* srow = sent + (row0 + r) * DIM + cg * 16;
        float4 v0 = *(const float4*)(srow + 0);
        float4 v1 = *(const float4*)(srow + 4);
        float4 v2 = *(const float4*)(srow + 8);
        float4 v3 = *(const float4*)(srow + 12);
        union { unsigned int u[4]; ushortx8 v; } p0, p1;
        p0.u[0] = cvt_pk_bf16(v0.x, v0.y); p0.u[1] = cvt_pk_bf16(v0.z, v0.w);
        p0.u[2] = cvt_pk_bf16(v1.x, v1.y); p0.u[3] = cvt_pk_bf16(v1.z, v1.w);
        p1.u[0] = cvt_pk_bf16(v2.x, v2.y); p1.u[1] = cvt_pk_bf16(v2.z, v2.w);
        p1.u[2] = cvt_pk_bf16(v3.x, v3.y); p1.u[3] = cvt_pk_bf16(v3.z, v3.w);
        *(ushortx8*)&As[cg * 2][r][0] = p0.v;
        *(ushortx8*)&As[cg * 2 + 1][r][0] = p1.v;
    }
    __syncthreads();

    floatx4 acc[4];
#pragma unroll
    for (int nt = 0; nt < 4; nt++) acc[nt] = (floatx4)(0.f);
    const bf16x8* wv8 = (const bf16x8*)wsp;
#pragma unroll
    for (int step = 0; step < 8; step++) {
        bf16x8 a = *(const bf16x8*)&As[l4 + step * 4][l15][0];
#pragma unroll
        for (int nt = 0; nt < 4; nt++) {
            int c = wv * 64 + nt * 16 + l15;
            bf16x8 bfr = wv8[(size_t)(l4 + step * 4) * 256 + c];
            acc[nt] = __builtin_amdgcn_mfma_f32_16x16x32_bf16(a, bfr, acc[nt], 0, 0, 0);
        }
    }
    // C layout: col = lane&15 (per n-tile), row = (lane>>4)*4 + reg
    float ep[4] = {0.f, 0.f, 0.f, 0.f};
#pragma unroll
    for (int nt = 0; nt < 4; nt++) {
        int c = wv * 64 + nt * 16 + l15;
        float al = attn_l[c];
#pragma unroll
        for (int r = 0; r < 4; r++) {
            int row = (int)row0 + l4 * 4 + r;
            feat16[(size_t)row * DIM + c] = f2bf(acc[nt][r]);
            ep[r] = fmaf(acc[nt][r], al, ep[r]);
        }
    }
#pragma unroll
    for (int m = 1; m < 16; m <<= 1) {
#pragma unroll
        for (int r = 0; r < 4; r++) ep[r] += __shfl_xor(ep[r], m, 64);
    }
    if (l15 == 0) {
#pragma unroll
        for (int r = 0; r < 4; r++)
            el[((size_t)row0 + l4 * 4 + r) * NH + wv] = ep[r];
    }
}

// ---------------- scatter: 2 edges/thread, issue-ahead ILP ----------------
// Block covers 512 edges [base+b*512, base+b*512+512); thread t handles
// slots t and t+256.  All 4 index loads issue before the (independent)
// atomics; stores last.  Launched as two halves for top-5 visibility.
__global__ __launch_bounds__(256) void scatter_edges(
    const int* __restrict__ src, const int* __restrict__ dst,
    int* __restrict__ count, unsigned short* __restrict__ bucket,
    int base, int limit)
{
    int eA = base + blockIdx.x * 512 + threadIdx.x;
    int eB = eA + 256;
    bool vA = eA < limit, vB = eB < limit;
    int wA = 0, wB = 0, sA = 0, sB = 0;
    if (vA) { wA = dst[eA]; sA = src[eA]; }
    if (vB) { wB = dst[eB]; sB = src[eB]; }
    int pA = 0, pB = 0;
    if (vA) pA = atomicAdd(&count[wA], 1);
    if (vB) pB = atomicAdd(&count[wB], 1);
    if (vA && pA < CAP) bucket[(size_t)wA * CAP + pA] = (unsigned short)sA;
    if (vB && pB < CAP) bucket[(size_t)wB * CAP + pB] = (unsigned short)sB;
}

// ---------------- GAT v2: ONE node per wave, async-staged gather ----------
__global__ __launch_bounds__(256) void gat_h(
    const int* __restrict__ count, const unsigned short* __restrict__ bucket,
    const float* __restrict__ el, const float* __restrict__ Cdst,
    const unsigned short* __restrict__ feat16, const float* __restrict__ word,
    const float* __restrict__ gat_bias, unsigned short* hb, int node0)
{
    __shared__ unsigned short Fs[4][8][256];  // staged feat rows, 16 KB
    __shared__ float abuf[4][64][4];          // alpha[slot][head], 4 KB
    int tid = threadIdx.x;
    int lane = tid & 63, wv = tid >> 6;
    int node = node0 + blockIdx.x * 4 + wv;

    // ---- speculative early issues ----
    int deg = count[node];
    int sraw = bucket[(size_t)node * CAP + lane];
    float4 wrow = *(const float4*)(word + (size_t)node * DIM + lane * 4);
    int s = sraw < NS ? sraw : NS - 1;
    float4 el4 = *(const float4*)(el + (size_t)s * 4);

    // ---- stage first 8 feat rows to LDS (overlaps er/softmax below) ----
#pragma unroll
    for (int j = 0; j < 4; j++) {
        int sA = __shfl(s, 2 * j, 64);
        int sB = __shfl(s, 2 * j + 1, 64);
        int srow = (lane < 32) ? sA : sB;
        gload_lds16(feat16 + (size_t)srow * DIM + (lane & 31) * 8, &Fs[wv][2 * j][0]);
    }

    // ---- er[h] = sum_c word[c] * Cdst[c][h], reduced over 64 lanes ----
    const float4* Cv = (const float4*)Cdst;
    float p0 = 0.f, p1 = 0.f, p2 = 0.f, p3 = 0.f;
    {
        float wc[4] = {wrow.x, wrow.y, wrow.z, wrow.w};
#pragma unroll
        for (int j = 0; j < 4; j++) {
            float4 ch = Cv[lane * 4 + j];
            p0 = fmaf(wc[j], ch.x, p0); p1 = fmaf(wc[j], ch.y, p1);
            p2 = fmaf(wc[j], ch.z, p2); p3 = fmaf(wc[j], ch.w, p3);
        }
    }
#pragma unroll
    for (int m = 1; m < 64; m <<= 1) {
        p0 += __shfl_xor(p0, m, 64); p1 += __shfl_xor(p1, m, 64);
        p2 += __shfl_xor(p2, m, 64); p3 += __shfl_xor(p3, m, 64);
    }

    // ---- scores: slot = lane; exp directly (bounded, no max pass) ----
    int dg = deg > CAP ? CAP : deg;
    float x0 = 0.f, x1 = 0.f, x2 = 0.f, x3 = 0.f;
    if (lane < dg) {
        float v;
        v = el4.x + p0; x0 = __expf(v > 0.f ? v : NEG_SLOPE * v);
        v = el4.y + p1; x1 = __expf(v > 0.f ? v : NEG_SLOPE * v);
        v = el4.z + p2; x2 = __expf(v > 0.f ? v : NEG_SLOPE * v);
        v = el4.w + p3; x3 = __expf(v > 0.f ? v : NEG_SLOPE * v);
    }
    float d0 = x0, d1 = x1, d2 = x2, d3 = x3;
#pragma unroll
    for (int m = 1; m < 64; m <<= 1) {
        d0 += __shfl_xor(d0, m, 64); d1 += __shfl_xor(d1, m, 64);
        d2 += __shfl_xor(d2, m, 64); d3 += __shfl_xor(d3, m, 64);
    }
    float4 av;
    av.x = x0 * (1.f / d0); av.y = x1 * (1.f / d1);
    av.z = x2 * (1.f / d2); av.w = x3 * (1.f / d3);
    *(float4*)&abuf[wv][lane][0] = av;   // NaN if dg==0, never read

    // ---- gather: 4 cols per lane; staged slots from LDS, tail from global ----
    int hh = lane >> 4;
    float a0 = 0.f, a1 = 0.f, a2 = 0.f, a3 = 0.f;
    asm volatile("s_waitcnt vmcnt(0)" ::: "memory");  // staged rows landed
    int nst = dg < 8 ? dg : 8;
    for (int i = 0; i < nst; i++) {
        float aa = abuf[wv][i][hh];
        ushort4 f = *(const ushort4*)&Fs[wv][i][lane * 4];
        a0 = fmaf(aa, bf2f(f.x), a0); a1 = fmaf(aa, bf2f(f.y), a1);
        a2 = fmaf(aa, bf2f(f.z), a2); a3 = fmaf(aa, bf2f(f.w), a3);
    }
    for (int i = 8; i < dg; i++) {
        int si = __shfl(s, i, 64);
        float aa = abuf[wv][i][hh];
        ushort4 f = *(const ushort4*)&feat16[(size_t)si * DIM + lane * 4];
        a0 = fmaf(aa, bf2f(f.x), a0); a1 = fmaf(aa, bf2f(f.y), a1);
        a2 = fmaf(aa, bf2f(f.z), a2); a3 = fmaf(aa, bf2f(f.w), a3);
    }

    // ---- epilogue: +bias, ELU, +residual, bf16 store ----
    float4 gb = *(const float4*)(gat_bias + lane * 4);
    float r0 = a0 + gb.x, r1 = a1 + gb.y, r2 = a2 + gb.z, r3 = a3 + gb.w;
    r0 = r0 > 0.f ? r0 : (__expf(r0) - 1.f);
    r1 = r1 > 0.f ? r1 : (__expf(r1) - 1.f);
    r2 = r2 > 0.f ? r2 : (__expf(r2) - 1.f);
    r3 = r3 > 0.f ? r3 : (__expf(r3) - 1.f);
    unsigned int lo = cvt_pk_bf16(wrow.x + r0, wrow.y + r1);
    unsigned int hi = cvt_pk_bf16(wrow.z + r2, wrow.w + r3);
    uint2 o; o.x = lo; o.y = hi;
    *(uint2*)&hb[(size_t)node * 512 + 256 + lane * 4] = o;
}

// ---------------- Fused FFN v3 (reverted known-good): BM=256, 8 waves ------
// H in regs, weights LDS-double-buffered, one barrier per chunk.  blk0 shifts
// the block index so the kernel can be launched as two half-grids.
__global__ __launch_bounds__(512, 2) void ffn_fused3(
    const unsigned short* hb,                // = (ushort*)d_out (aliases out!)
    const unsigned short* __restrict__ w1p,
    const float* __restrict__ b1,
    const unsigned short* __restrict__ w2p,
    const float* __restrict__ b2,
    float* out, int blk0)
{
    __shared__ unsigned short W1s[2][8192];  // 16 KB each
    __shared__ unsigned short W2s[2][8192];
    int tid = threadIdx.x;
    int lane = tid & 63, wv = tid >> 6;
    int l31 = lane & 31, half = lane >> 5;
    int row0 = (blk0 + blockIdx.x) * 256;

    int myrow = row0 + wv * 32 + l31;
    if (myrow >= NW) myrow = NW - 1;
    const unsigned short* hrow = hb + (size_t)myrow * 512 + 256 + half * 8;
    bf16x8 hreg[16];
#pragma unroll
    for (int ks = 0; ks < 16; ks++)
        hreg[ks] = *(const bf16x8*)(hrow + ks * 16);

    // stage chunk 0
    {
        if (wv < 4) {
#pragma unroll
            for (int it = 0; it < 4; it++) {
                int q = wv * 4 + it;
                const unsigned short* s =
                    w1p + ((size_t)(q * 2 + (lane >> 5)) * 512 + (lane & 31)) * 8;
                gload_lds16(s, &W1s[0][q * 512]);
            }
        } else {
#pragma unroll
            for (int it = 0; it < 4; it++) {
                int qq = (wv - 4) * 4 + it;
                const unsigned short* s = w2p + ((size_t)qq * 64 + lane) * 8;
                gload_lds16(s, &W2s[0][qq * 512]);
            }
        }
    }

    floatx16 oacc[8];
#pragma unroll
    for (int j = 0; j < 8; j++) oacc[j] = (floatx16)(0.f);
    __syncthreads();

#pragma unroll 2
    for (int hbi = 0; hbi < 16; hbi++) {
        int cur = hbi & 1;
        if (hbi < 15) {
            int c = hbi + 1, nb = cur ^ 1;
            if (wv < 4) {
#pragma unroll
                for (int it = 0; it < 4; it++) {
                    int q = wv * 4 + it;
                    const unsigned short* s =
                        w1p + ((size_t)(q * 2 + (lane >> 5)) * 512 + c * 32 + (lane & 31)) * 8;
                    gload_lds16(s, &W1s[nb][q * 512]);
                }
            } else {
#pragma unroll
                for (int it = 0; it < 4; it++) {
                    int qq = (wv - 4) * 4 + it;
                    const unsigned short* s = w2p + ((size_t)c * 1024 + qq * 64 + lane) * 8;
                    gload_lds16(s, &W2s[nb][qq * 512]);
                }
            }
        }
        const bf16x8* W1v = (const bf16x8*)W1s[cur];
        floatx16 hacc = (floatx16)(0.f);
#pragma unroll
        for (int ks = 0; ks < 16; ks++) {
            bf16x8 afrag = W1v[(ks * 2 + half) * 32 + l31];
            hacc = __builtin_amdgcn_mfma_f32_32x32x16_bf16(afrag, hreg[ks], hacc, 0, 0, 0);
        }
        const float* b1b = b1 + hbi * 32 + 4 * half;
        float4 bb0 = *(const float4*)(b1b + 0);
        float4 bb1 = *(const float4*)(b1b + 8);
        float4 bb2 = *(const float4*)(b1b + 16);
        float4 bb3 = *(const float4*)(b1b + 24);
        float bs[16] = {bb0.x, bb0.y, bb0.z, bb0.w, bb1.x, bb1.y, bb1.z, bb1.w,
                        bb2.x, bb2.y, bb2.z, bb2.w, bb3.x, bb3.y, bb3.z, bb3.w};
        float p[16];
#pragma unroll
        for (int j = 0; j < 16; j++) {
            float v = hacc[j] + bs[j];
            p[j] = v > 0.f ? v : 0.f;
        }
        unsigned int pk0 = cvt_pk_bf16(p[0], p[1]),   pk1 = cvt_pk_bf16(p[2], p[3]);
        unsigned int pk2 = cvt_pk_bf16(p[4], p[5]),   pk3 = cvt_pk_bf16(p[6], p[7]);
        unsigned int pk4 = cvt_pk_bf16(p[8], p[9]),   pk5 = cvt_pk_bf16(p[10], p[11]);
        unsigned int pk6 = cvt_pk_bf16(p[12], p[13]), pk7 = cvt_pk_bf16(p[14], p[15]);
        permlane32_swap(pk0, pk2);
        permlane32_swap(pk1, pk3);
        permlane32_swap(pk4, pk6);
        permlane32_swap(pk5, pk7);
        union { unsigned int u[4]; bf16x8 v; } f0, f1;
        f0.u[0] = pk0; f0.u[1] = pk1; f0.u[2] = pk2; f0.u[3] = pk3;  // hid 0..15
        f1.u[0] = pk4; f1.u[1] = pk5; f1.u[2] = pk6; f1.u[3] = pk7;  // hid 16..31
        const bf16x8* W2v = (const bf16x8*)W2s[cur];
#pragma unroll
        for (int ks2 = 0; ks2 < 2; ks2++) {
            bf16x8 pa = ks2 ? f1.v : f0.v;
#pragma unroll
            for (int ct = 0; ct < 8; ct++) {
                bf16x8 bfr = W2v[(ks2 * 2 + half) * 256 + ct * 32 + l31];
                oacc[ct] = __builtin_amdgcn_mfma_f32_32x32x16_bf16(pa, bfr, oacc[ct], 0, 0, 0);
            }
        }
        if (hbi < 15) __syncthreads();
    }
#pragma unroll
    for (int ct = 0; ct < 8; ct++) {
        int c = ct * 32 + l31;
        float bias = b2[c];
#pragma unroll
        for (int reg = 0; reg < 16; reg++) {
            int rloc = row0 + wv * 32 + (reg & 3) + 8 * (reg >> 2) + 4 * half;
            if (rloc < NW) out[(size_t)rloc * DIM + c] = oacc[ct][reg] + bias;
        }
    }
}

// ---------------- launch ----------------
extern "C" void kernel_launch(void* const* d_in, const int* in_sizes, int n_in,
                              void* d_out, int out_size, void* d_ws, size_t ws_size,
                              hipStream_t stream) {
    const float* word   = (const float*)d_in[0];
    const float* sent   = (const float*)d_in[1];
    const int*   src    = (const int*)d_in[2];
    const int*   dst    = (const int*)d_in[3];
    const float* W_src  = (const float*)d_in[4];
    const float* W_dst  = (const float*)d_in[5];
    const float* attn_l = (const float*)d_in[6];
    const float* attn_r = (const float*)d_in[7];
    const float* gbias  = (const float*)d_in[8];
    const float* w1     = (const float*)d_in[9];
    const float* b1     = (const float*)d_in[10];
    const float* w2     = (const float*)d_in[11];
    const float* b2     = (const float*)d_in[12];
    float* out = (float*)d_out;
    // hbf row n interleaved into d_out bytes [1024n+512, 1024n+1024)
    unsigned short* hb = (unsigned short*)d_out;

    char* wsb = (char*)d_ws;
    unsigned short* w1p = (unsigned short*)wsb;                 // 512*256
    unsigned short* w2p = w1p + (size_t)DFF * 256;              // 256*512
    unsigned short* wsp = w2p + (size_t)256 * DFF;              // 256*256
    float* el    = (float*)(wsp + (size_t)DIM * DIM);           // NS*4
    float* C_dst = el + (size_t)NS * NH;                        // 256*4
    unsigned short* feat16 = (unsigned short*)(C_dst + DIM * NH);  // NS*256
    int* count = (int*)(feat16 + (size_t)NS * DIM);             // NW
    unsigned short* bucket = (unsigned short*)(count + NW);     // NW*CAP

    hipMemsetAsync(count, 0, (size_t)NW * sizeof(int), stream);
    // scatter halves (512 edges per block)
    hipLaunchKernelGGL(scatter_edges, dim3(782), dim3(256), 0, stream,
                       src, dst, count, bucket, 0, NE / 2);
    hipLaunchKernelGGL(scatter_edges, dim3(782), dim3(256), 0, stream,
                       src, dst, count, bucket, NE / 2, NE);
    hipLaunchKernelGGL(prep_all, dim3(1 + DFF + 256 + 256), dim3(256), 0, stream,
                       W_src, W_dst, attn_r, w1, w2, C_dst, w1p, w2p, wsp);
    hipLaunchKernelGGL(feat_el, dim3(NS / 16), dim3(256), 0, stream,
                       sent, wsp, attn_l, feat16, el);
    hipLaunchKernelGGL(gat_h, dim3(NW / 8), dim3(256), 0, stream,
                       count, bucket, el, C_dst, feat16, word, gbias, hb, 0);
    hipLaunchKernelGGL(gat_h, dim3(NW / 8), dim3(256), 0, stream,
                       count, bucket, el, C_dst, feat16, word, gbias, hb, NW / 2);
    // ffn halves (391 = 196 + 195)
    hipLaunchKernelGGL(ffn_fused3, dim3(196), dim3(512), 0, stream,
                       hb, w1p, b1, w2p, b2, out, 0);
    hipLaunchKernelGGL(ffn_fused3, dim3(195), dim3(512), 0, stream,
                       hb, w1p, b1, w2p, b2, out, 196);
}